// Round 1
// baseline (457.181 us; speedup 1.0000x reference)
//
#include <hip/hip_runtime.h>

typedef _Float16 v8h __attribute__((ext_vector_type(8)));
typedef _Float16 v4h __attribute__((ext_vector_type(4)));
typedef float    v4f __attribute__((ext_vector_type(4)));

// ---------------- Kernel 1: style modulation s[b][c] = style[b]·mod_weight[c] + bias[c]
__global__ void style_kernel(const float* __restrict__ style,
                             const float* __restrict__ mw,
                             const float* __restrict__ mb,
                             float* __restrict__ s_out) {
    const int b = blockIdx.x;          // 16 blocks
    const int t = threadIdx.x;         // 256 threads
    const int c = t >> 2, q = t & 3;   // 4 threads per channel, 128 elems each
    const float* st = style + b * 512 + q * 128;
    const float* w  = mw + c * 512 + q * 128;
    float acc = 0.f;
    #pragma unroll 8
    for (int i = 0; i < 128; ++i) acc += st[i] * w[i];
    acc += __shfl_xor(acc, 1);
    acc += __shfl_xor(acc, 2);
    if (q == 0) s_out[b * 64 + c] = acc + mb[c];
}

// ---------------- Kernel 2: modulate + demodulate + repack weights into A-fragment layout
// wA layout: [b][tap][ks][otile][lane][j]  (f16), lane l holds o = otile*16 + (l&15),
// k(channel) = ks*32 + (l>>4)*8 + j  -> matches mfma_f32_16x16x32 A-operand layout.
__global__ void wprep_kernel(const float* __restrict__ weight,
                             const float* __restrict__ s,
                             _Float16* __restrict__ wA) {
    const int blk = blockIdx.x;            // 1024 = B*O
    const int b = blk >> 6, o = blk & 63;
    const int lane = threadIdx.x;          // 64
    const float* wo = weight + o * 576;    // weight[0][o][c][kh][kw]
    const float* sb = s + b * 64;
    float vals[9];
    float sum = 0.f;
    #pragma unroll
    for (int k = 0; k < 9; ++k) {
        int e = lane + k * 64;             // 0..575
        int c = e / 9;
        float v = wo[e] * sb[c];
        vals[k] = v;
        sum += v * v;
    }
    #pragma unroll
    for (int off = 32; off; off >>= 1) sum += __shfl_xor(sum, off);
    const float demod = 1.f / sqrtf(sum + 1e-8f);
    #pragma unroll
    for (int k = 0; k < 9; ++k) {
        int e = lane + k * 64;
        int c = e / 9, tap = e - c * 9;
        int ks = c >> 5, lg = (c >> 3) & 3, j = c & 7;
        int dst = (((b * 9 + tap) * 8 + ks * 4 + (o >> 4)) * 64 + lg * 16 + (o & 15)) * 8 + j;
        wA[dst] = (_Float16)(vals[k] * demod);
    }
}

// ---------------- Kernel 3: implicit-GEMM conv via MFMA
// block = (tile_x, tile_y, b); 256 threads = 4 waves.
// Each wave: rows 4*wv..4*wv+3 of the 16x16 tile, all 4 o-tiles (M=64).
// x halo tile (18x18 pixels x 64ch) staged in LDS channel-last f16, XOR-swizzled.
__global__ __launch_bounds__(256)
void conv_kernel(const float* __restrict__ x,
                 const _Float16* __restrict__ wA,
                 float* __restrict__ out) {
    __shared__ _Float16 lds[18 * 18 * 64];   // 41472 B

    const int tid = threadIdx.x;
    const int b  = blockIdx.z;
    const int h0 = blockIdx.y << 4;
    const int w0 = blockIdx.x << 4;

    // ---- stage x halo tile -> LDS (channel-last, swizzled)
    const float* xb = x + ((size_t)b << 22);  // b*64*65536
    for (int idx = tid; idx < 5184; idx += 256) {   // 324 pixels * 16 c-quads
        int q   = idx / 324;        // channel quad: c0 = 4q
        int pix = idx - q * 324;    // 0..323
        int ph  = pix / 18;
        int pw  = pix - ph * 18;
        int h = h0 - 1 + ph, w = w0 - 1 + pw;
        bool ok = ((unsigned)h < 256u) & ((unsigned)w < 256u);
        const float* xp = xb + ((long)q << 18) + (long)(h * 256 + w);
        float f0 = ok ? xp[0]          : 0.f;
        float f1 = ok ? xp[1 << 16]    : 0.f;
        float f2 = ok ? xp[2 << 16]    : 0.f;
        float f3 = ok ? xp[3 << 16]    : 0.f;
        v4h v;
        v[0] = (_Float16)f0; v[1] = (_Float16)f1;
        v[2] = (_Float16)f2; v[3] = (_Float16)f3;
        int g = q >> 1;                       // 16B granule = 8 channels
        int addr = pix * 128 + (((g ^ (pix & 7)) << 4)) + ((q & 1) << 3);
        *reinterpret_cast<v4h*>(reinterpret_cast<char*>(lds) + addr) = v;
    }
    __syncthreads();

    const int lane = tid & 63, wv = tid >> 6;
    const int n = lane & 15, lg = lane >> 4;

    v4f acc[4][4];
    #pragma unroll
    for (int ot = 0; ot < 4; ++ot)
        #pragma unroll
        for (int r = 0; r < 4; ++r)
            acc[ot][r] = (v4f)0.f;

    const _Float16* wab = wA + (size_t)b * (9 * 8 * 64 * 8);

    #pragma unroll
    for (int t = 0; t < 9; ++t) {
        const int dh = t / 3, dw = t - dh * 3;
        v8h a[4][2];
        #pragma unroll
        for (int ot = 0; ot < 4; ++ot)
            #pragma unroll
            for (int ks = 0; ks < 2; ++ks)
                a[ot][ks] = *reinterpret_cast<const v8h*>(
                    wab + ((size_t)((t * 8 + ks * 4 + ot) * 64 + lane)) * 8);
        #pragma unroll
        for (int r = 0; r < 4; ++r) {
            const int row = wv * 4 + r;
            const int pix = (row + dh) * 18 + n + dw;
            const int pxh = pix * 128, px7 = pix & 7;
            #pragma unroll
            for (int ks = 0; ks < 2; ++ks) {
                v8h bf = *reinterpret_cast<const v8h*>(
                    reinterpret_cast<char*>(lds) + pxh + ((((ks << 2) + lg) ^ px7) << 4));
                #pragma unroll
                for (int ot = 0; ot < 4; ++ot)
                    acc[ot][r] = __builtin_amdgcn_mfma_f32_16x16x32_f16(
                        a[ot][ks], bf, acc[ot][r], 0, 0, 0);
            }
        }
    }

    // ---- epilogue: D frag -> out[b][o][h][w]; row=(l>>4)*4+reg (o), col=l&15 (w)
    #pragma unroll
    for (int ot = 0; ot < 4; ++ot) {
        #pragma unroll
        for (int r = 0; r < 4; ++r) {
            const int h = h0 + wv * 4 + r;
            #pragma unroll
            for (int reg = 0; reg < 4; ++reg) {
                const int o = ot * 16 + lg * 4 + reg;
                out[((size_t)(b * 64 + o) << 16) + (h << 8) + (w0 + n)] = acc[ot][r][reg];
            }
        }
    }
}

extern "C" void kernel_launch(void* const* d_in, const int* in_sizes, int n_in,
                              void* d_out, int out_size, void* d_ws, size_t ws_size,
                              hipStream_t stream) {
    const float* x      = (const float*)d_in[0];
    const float* style  = (const float*)d_in[1];
    const float* mw     = (const float*)d_in[2];
    const float* mb     = (const float*)d_in[3];
    const float* weight = (const float*)d_in[4];
    float* out = (float*)d_out;

    float*    s_ws = (float*)d_ws;                         // 1024 floats
    _Float16* wA   = (_Float16*)((char*)d_ws + 4096);      // 589824 f16 = 1.18 MB

    style_kernel<<<16, 256, 0, stream>>>(style, mw, mb, s_ws);
    wprep_kernel<<<1024, 64, 0, stream>>>(weight, s_ws, wA);
    conv_kernel<<<dim3(16, 16, 16), 256, 0, stream>>>(x, wA, out);
}

// Round 2
// 262.039 us; speedup vs baseline: 1.7447x; 1.7447x over previous
//
#include <hip/hip_runtime.h>

typedef _Float16 v8h __attribute__((ext_vector_type(8)));
typedef _Float16 v4h __attribute__((ext_vector_type(4)));
typedef float    v4f __attribute__((ext_vector_type(4)));

// ---------------- Kernel 1: style modulation s[b][c] = style[b]·mod_weight[c] + bias[c]
__global__ void style_kernel(const float* __restrict__ style,
                             const float* __restrict__ mw,
                             const float* __restrict__ mb,
                             float* __restrict__ s_out) {
    const int b = blockIdx.x;          // 16 blocks
    const int t = threadIdx.x;         // 256 threads
    const int c = t >> 2, q = t & 3;   // 4 threads per channel, 128 elems each
    const float* st = style + b * 512 + q * 128;
    const float* w  = mw + c * 512 + q * 128;
    float acc = 0.f;
    #pragma unroll 8
    for (int i = 0; i < 128; ++i) acc += st[i] * w[i];
    acc += __shfl_xor(acc, 1);
    acc += __shfl_xor(acc, 2);
    if (q == 0) s_out[b * 64 + c] = acc + mb[c];
}

// ---------------- Kernel 2: modulate + demodulate + repack weights into A-fragment layout
__global__ void wprep_kernel(const float* __restrict__ weight,
                             const float* __restrict__ s,
                             _Float16* __restrict__ wA) {
    const int blk = blockIdx.x;            // 1024 = B*O
    const int b = blk >> 6, o = blk & 63;
    const int lane = threadIdx.x;          // 64
    const float* wo = weight + o * 576;    // weight[0][o][c][kh][kw]
    const float* sb = s + b * 64;
    float vals[9];
    float sum = 0.f;
    #pragma unroll
    for (int k = 0; k < 9; ++k) {
        int e = lane + k * 64;             // 0..575
        int c = e / 9;
        float v = wo[e] * sb[c];
        vals[k] = v;
        sum += v * v;
    }
    #pragma unroll
    for (int off = 32; off; off >>= 1) sum += __shfl_xor(sum, off);
    const float demod = 1.f / sqrtf(sum + 1e-8f);
    #pragma unroll
    for (int k = 0; k < 9; ++k) {
        int e = lane + k * 64;
        int c = e / 9, tap = e - c * 9;
        int ks = c >> 5, lg = (c >> 3) & 3, j = c & 7;
        int dst = (((b * 9 + tap) * 8 + ks * 4 + (o >> 4)) * 64 + lg * 16 + (o & 15)) * 8 + j;
        wA[dst] = (_Float16)(vals[k] * demod);
    }
}

// ---------------- Kernel 2b: x (B,64,256,256) f32 NCHW -> padded NHWC f16 (B,258,258,64)
__global__ __launch_bounds__(256)
void xprep_kernel(const float* __restrict__ x, _Float16* __restrict__ xh) {
    const int ph = blockIdx.x;   // 0..257 padded row
    const int b  = blockIdx.y;
    const int tid = threadIdx.x;
    _Float16* rowp = xh + (size_t)(b * 258 + ph) * (258 * 64);
    if (ph == 0 || ph == 257) {                 // top/bottom zero border
        v8h z = {};
        for (int i = tid; i < 258 * 8; i += 256)
            *reinterpret_cast<v8h*>(rowp + (size_t)i * 8) = z;
        return;
    }
    if (tid < 16) {                             // left/right zero border pixels
        v8h z = {};
        int pw = (tid >> 3) ? 257 : 0;
        *reinterpret_cast<v8h*>(rowp + pw * 64 + (tid & 7) * 8) = z;
    }
    const int h = ph - 1;
    const int w = tid;                          // 0..255
    const float* xp = x + ((size_t)b << 22) + ((size_t)h << 8) + w;
    _Float16* op = rowp + (w + 1) * 64;
    #pragma unroll
    for (int c0 = 0; c0 < 8; ++c0) {
        v8h v;
        #pragma unroll
        for (int j = 0; j < 8; ++j)
            v[j] = (_Float16)xp[(size_t)(c0 * 8 + j) << 16];
        *reinterpret_cast<v8h*>(op + c0 * 8) = v;
    }
}

// ---------------- Kernel 3: implicit-GEMM conv via MFMA, staging from padded NHWC f16
// LDS holds 18x18 pixels x 64ch f16, pixel-major, XOR-swizzled granules.
// Staged via global_load_lds (linear LDS dest, pre-swizzled global source).
__global__ __launch_bounds__(256)
void conv_kernel(const _Float16* __restrict__ xh,
                 const _Float16* __restrict__ wA,
                 float* __restrict__ out) {
    __shared__ __align__(16) _Float16 lds[324 * 64];   // 41472 B

    const int tid = threadIdx.x;
    const int b  = blockIdx.z;
    const int h0 = blockIdx.y << 4;   // also the padded-coord of the halo start
    const int w0 = blockIdx.x << 4;

    const _Float16* xhb = xh + (size_t)b * (258 * 258 * 64);
    // stage: 324 pixels * 8 granules(16B) = 2592 lane-loads
    for (int idx = tid; idx < 2592; idx += 256) {
        int pix = idx >> 3, g = idx & 7;
        int ph = pix / 18, pw = pix - ph * 18;
        const _Float16* src = xhb + (size_t)((h0 + ph) * 258 + (w0 + pw)) * 64
                                  + ((g ^ (pix & 7)) << 3);
        __builtin_amdgcn_global_load_lds(
            (const __attribute__((address_space(1))) void*)src,
            (__attribute__((address_space(3))) void*)(lds + idx * 8),
            16, 0, 0);
    }
    __syncthreads();

    const int lane = tid & 63, wv = tid >> 6;
    const int n = lane & 15, lg = lane >> 4;

    v4f acc[4][4];
    #pragma unroll
    for (int ot = 0; ot < 4; ++ot)
        #pragma unroll
        for (int r = 0; r < 4; ++r)
            acc[ot][r] = (v4f)0.f;

    const _Float16* wab = wA + (size_t)b * (9 * 8 * 64 * 8);

    #pragma unroll
    for (int t = 0; t < 9; ++t) {
        const int dh = t / 3, dw = t - dh * 3;
        v8h a[4][2];
        #pragma unroll
        for (int ot = 0; ot < 4; ++ot)
            #pragma unroll
            for (int ks = 0; ks < 2; ++ks)
                a[ot][ks] = *reinterpret_cast<const v8h*>(
                    wab + ((size_t)((t * 8 + ks * 4 + ot) * 64 + lane)) * 8);
        #pragma unroll
        for (int r = 0; r < 4; ++r) {
            const int row = wv * 4 + r;
            const int pix = (row + dh) * 18 + n + dw;
            const int pxh = pix * 128, px7 = pix & 7;
            #pragma unroll
            for (int ks = 0; ks < 2; ++ks) {
                v8h bf = *reinterpret_cast<const v8h*>(
                    reinterpret_cast<char*>(lds) + pxh + ((((ks << 2) + lg) ^ px7) << 4));
                #pragma unroll
                for (int ot = 0; ot < 4; ++ot)
                    acc[ot][r] = __builtin_amdgcn_mfma_f32_16x16x32_f16(
                        a[ot][ks], bf, acc[ot][r], 0, 0, 0);
            }
        }
    }

    #pragma unroll
    for (int ot = 0; ot < 4; ++ot) {
        #pragma unroll
        for (int r = 0; r < 4; ++r) {
            const int h = h0 + wv * 4 + r;
            #pragma unroll
            for (int reg = 0; reg < 4; ++reg) {
                const int o = ot * 16 + lg * 4 + reg;
                out[((size_t)(b * 64 + o) << 16) + (h << 8) + (w0 + n)] = acc[ot][r][reg];
            }
        }
    }
}

// ---------------- Fallback conv (stages directly from NCHW f32) if d_ws too small
__global__ __launch_bounds__(256)
void conv_kernel_nofit(const float* __restrict__ x,
                       const _Float16* __restrict__ wA,
                       float* __restrict__ out) {
    __shared__ __align__(16) _Float16 lds[324 * 64];
    const int tid = threadIdx.x;
    const int b  = blockIdx.z;
    const int h0 = blockIdx.y << 4;
    const int w0 = blockIdx.x << 4;
    const float* xb = x + ((size_t)b << 22);
    for (int idx = tid; idx < 5184; idx += 256) {
        int q   = idx / 324;
        int pix = idx - q * 324;
        int ph  = pix / 18;
        int pw  = pix - ph * 18;
        int h = h0 - 1 + ph, w = w0 - 1 + pw;
        bool ok = ((unsigned)h < 256u) & ((unsigned)w < 256u);
        const float* xp = xb + ((long)q << 18) + (long)(h * 256 + w);
        float f0 = ok ? xp[0]       : 0.f;
        float f1 = ok ? xp[1 << 16] : 0.f;
        float f2 = ok ? xp[2 << 16] : 0.f;
        float f3 = ok ? xp[3 << 16] : 0.f;
        v4h v;
        v[0] = (_Float16)f0; v[1] = (_Float16)f1;
        v[2] = (_Float16)f2; v[3] = (_Float16)f3;
        int g = q >> 1;
        int addr = pix * 128 + ((g ^ (pix & 7)) << 4) + ((q & 1) << 3);
        *reinterpret_cast<v4h*>(reinterpret_cast<char*>(lds) + addr) = v;
    }
    __syncthreads();
    const int lane = tid & 63, wv = tid >> 6;
    const int n = lane & 15, lg = lane >> 4;
    v4f acc[4][4];
    #pragma unroll
    for (int ot = 0; ot < 4; ++ot)
        #pragma unroll
        for (int r = 0; r < 4; ++r) acc[ot][r] = (v4f)0.f;
    const _Float16* wab = wA + (size_t)b * (9 * 8 * 64 * 8);
    #pragma unroll
    for (int t = 0; t < 9; ++t) {
        const int dh = t / 3, dw = t - dh * 3;
        v8h a[4][2];
        #pragma unroll
        for (int ot = 0; ot < 4; ++ot)
            #pragma unroll
            for (int ks = 0; ks < 2; ++ks)
                a[ot][ks] = *reinterpret_cast<const v8h*>(
                    wab + ((size_t)((t * 8 + ks * 4 + ot) * 64 + lane)) * 8);
        #pragma unroll
        for (int r = 0; r < 4; ++r) {
            const int row = wv * 4 + r;
            const int pix = (row + dh) * 18 + n + dw;
            const int pxh = pix * 128, px7 = pix & 7;
            #pragma unroll
            for (int ks = 0; ks < 2; ++ks) {
                v8h bf = *reinterpret_cast<const v8h*>(
                    reinterpret_cast<char*>(lds) + pxh + ((((ks << 2) + lg) ^ px7) << 4));
                #pragma unroll
                for (int ot = 0; ot < 4; ++ot)
                    acc[ot][r] = __builtin_amdgcn_mfma_f32_16x16x32_f16(
                        a[ot][ks], bf, acc[ot][r], 0, 0, 0);
            }
        }
    }
    #pragma unroll
    for (int ot = 0; ot < 4; ++ot)
        #pragma unroll
        for (int r = 0; r < 4; ++r) {
            const int h = h0 + wv * 4 + r;
            #pragma unroll
            for (int reg = 0; reg < 4; ++reg) {
                const int o = ot * 16 + lg * 4 + reg;
                out[((size_t)(b * 64 + o) << 16) + (h << 8) + (w0 + n)] = acc[ot][r][reg];
            }
        }
}

extern "C" void kernel_launch(void* const* d_in, const int* in_sizes, int n_in,
                              void* d_out, int out_size, void* d_ws, size_t ws_size,
                              hipStream_t stream) {
    const float* x      = (const float*)d_in[0];
    const float* style  = (const float*)d_in[1];
    const float* mw     = (const float*)d_in[2];
    const float* mb     = (const float*)d_in[3];
    const float* weight = (const float*)d_in[4];
    float* out = (float*)d_out;

    float*    s_ws = (float*)d_ws;                           // 1 KB used
    _Float16* wA   = (_Float16*)((char*)d_ws + 4096);        // 1.18 MB
    const size_t xh_off = 2u * 1024u * 1024u;
    _Float16* xh   = (_Float16*)((char*)d_ws + xh_off);      // 136.3 MB
    const size_t xh_bytes = (size_t)16 * 258 * 258 * 64 * 2;

    style_kernel<<<16, 256, 0, stream>>>(style, mw, mb, s_ws);
    wprep_kernel<<<1024, 64, 0, stream>>>(weight, s_ws, wA);

    if (ws_size >= xh_off + xh_bytes) {
        xprep_kernel<<<dim3(258, 16), 256, 0, stream>>>(x, xh);
        conv_kernel<<<dim3(16, 16, 16), 256, 0, stream>>>(xh, wA, out);
    } else {
        conv_kernel_nofit<<<dim3(16, 16, 16), 256, 0, stream>>>(x, wA, out);
    }
}